// Round 9
// baseline (134.349 us; speedup 1.0000x reference)
//
#include <hip/hip_runtime.h>
#include <stdint.h>

// Problem constants (fixed by the reference): P=8192, L=64, H=128.
#define PCNT 8192
#define LROW 64
#define HDIM 128
#define XSTR 136                    // x_lds k-stride (f16), 16B aligned
#define W1STR 136                   // W1^T k-stride (K=128 + 8 pad)
#define W23STR 264                  // W2^T/W3^T k-stride (K=256 + 8 pad)
#define W1_ELEMS (128 * W1STR)      // 17408
#define W23_ELEMS (128 * W23STR)    // 33792

typedef _Float16 f16;
typedef __attribute__((ext_vector_type(8))) _Float16 half8;
typedef __attribute__((ext_vector_type(4))) _Float16 half4v;
typedef __attribute__((ext_vector_type(2))) _Float16 half2v;
typedef __attribute__((ext_vector_type(4))) float f32x4;

#define MFMA16(A, B, C) __builtin_amdgcn_mfma_f32_16x16x32_f16((A), (B), (C), 0, 0, 0)

__device__ __forceinline__ half8 ldh8(const f16* p) {
  return *reinterpret_cast<const half8*>(p);
}

union PkU { uint32_t u; half2v h; };

__device__ __forceinline__ uint32_t pk2(float lo, float hi) {
  PkU a;
  a.h[0] = (f16)lo;
  a.h[1] = (f16)hi;
  return a.u;
}

__device__ __forceinline__ uint32_t pkmax(uint32_t a, uint32_t b) {
  uint32_t d;
  asm("v_pk_max_f16 %0, %1, %2" : "=v"(d) : "v"(a), "v"(b));
  return d;
}

// ---------------------------------------------------------------------------
// Prep: ws = 3 transposed fp16 weight buffers (fused-K layout):
//   buf0 @0:                 W1^T  [c][k], k<128 real, stride 136
//   buf1 @W1_ELEMS:          W2^T  [c][k], k<256 real (Wa2|Wb2), stride 264
//   buf2 @W1_ELEMS+W23_ELEMS W3^T  same, stride 264
// Total 84992 f16 = 169984 B.
// ---------------------------------------------------------------------------
__global__ void prep_weights(const float* __restrict__ W1,
                             const float* __restrict__ W2,
                             const float* __restrict__ W3,
                             f16* __restrict__ wt) {
  int idx = blockIdx.x * 256 + threadIdx.x;
  if (idx >= W1_ELEMS + 2 * W23_ELEMS) return;
  float v = 0.0f;
  if (idx < W1_ELEMS) {
    int c = idx / W1STR, k = idx - c * W1STR;
    if (k < 128) v = W1[k * 128 + c];
  } else {
    int rem = idx - W1_ELEMS;
    const float* W = (rem < W23_ELEMS) ? W2 : W3;
    if (rem >= W23_ELEMS) rem -= W23_ELEMS;
    int c = rem / W23STR, k = rem - c * W23STR;
    if (k < 256) v = W[k * 128 + c];
  }
  wt[idx] = (f16)v;
}

// ---------------------------------------------------------------------------
// Fused kernel, transposed-D layout (R3 lineage): 1 block (4 waves) per
// polyline; wave w owns output cols [32w,32w+32). Fused-K GEMM: for layers
// 1/2, K=256 with k>=128 B-fragments taken uniform from phib (phi replicated
// across lanes -> row-constant rank-1 term) — no separate pv phase. Bias
// seeds acc. One stats barrier/layer ([row][wave] float2, b128-pair reads),
// per-lane redundant mu/rstd, one phib barrier/layer.
// __launch_bounds__(256,4): proven 56-VGPR spill-free regime.
// ---------------------------------------------------------------------------
__global__ __launch_bounds__(256, 4)
void fused_subgraph(const float* __restrict__ hs,
                    const int* __restrict__ lens,
                    const f16* __restrict__ wt,
                    const float* __restrict__ b1, const float* __restrict__ g1, const float* __restrict__ be1,
                    const float* __restrict__ b2, const float* __restrict__ g2, const float* __restrict__ be2,
                    const float* __restrict__ b3, const float* __restrict__ g3, const float* __restrict__ be3,
                    float* __restrict__ out) {
  __shared__ __align__(16) f16 x_lds[LROW * XSTR];   // 17408 B
  __shared__ __align__(16) float2 stats_s[LROW][4];  // [row][wave] (sum, sumsq), 2 KB
  __shared__ __align__(16) f16 phib[HDIM];           // phi (masked col-max), fp16

  const int tid = threadIdx.x;
  const int w = tid >> 6;   // wave 0..3
  const int l = tid & 63;   // lane
  const int p = blockIdx.x;

  int len = lens[p];
  len = (len < 1) ? 1 : (len > LROW ? LROW : len);
  const int mtiles = (len + 15) >> 4;  // 1..4 M-tiles actually needed

  const int l15 = l & 15;
  const int lg = l >> 4;                    // lane group 0..3
  const int ko = lg * 8;                    // k offset within a 32-k tile
  const int cb0 = w * 32 + lg * 4;          // lane's col base, nt=0 (4 consecutive cols)
  const int cb1 = cb0 + 16;                 // nt=1

  // ---- stage input rows [0, 16*mtiles): fp32 -> fp16, b128 LDS writes ----
  {
    const float* hp = hs + (size_t)p * (LROW * HDIM);
    for (int it = 0; it < mtiles; ++it) {
      int e = (it * 256 + tid) * 8;
      int r = e >> 7, c = e & 127;
      float4 va = *reinterpret_cast<const float4*>(hp + e);
      float4 vb = *reinterpret_cast<const float4*>(hp + e + 4);
      half8 hv;
      hv[0] = (f16)va.x; hv[1] = (f16)va.y; hv[2] = (f16)va.z; hv[3] = (f16)va.w;
      hv[4] = (f16)vb.x; hv[5] = (f16)vb.y; hv[6] = (f16)vb.z; hv[7] = (f16)vb.w;
      *reinterpret_cast<half8*>(&x_lds[r * XSTR + c]) = hv;
    }
  }
  __syncthreads();

#pragma unroll
  for (int layer = 0; layer < 3; ++layer) {
    const float* gv  = (layer == 0) ? g1  : (layer == 1) ? g2  : g3;
    const float* bev = (layer == 0) ? be1 : (layer == 1) ? be2 : be3;
    const float* bv  = (layer == 0) ? b1  : (layer == 1) ? b2  : b3;
    const f16* wa = (layer == 0) ? wt
                   : (layer == 1) ? (wt + W1_ELEMS)
                                  : (wt + W1_ELEMS + W23_ELEMS);
    const int wstr = (layer == 0) ? W1STR : W23STR;
    const int kcN  = (layer == 0) ? 4 : 8;
    const int wrow0 = (w * 32 + l15) * wstr;
    const int wrow1 = wrow0 + 16 * wstr;

    // ---- GEMM: acc[mt] = bias + (x~ @ W~)^T,  K = 128 or 256 (fused pv) ----
    f32x4 acc[4][2];
    {
      const float4 bl0 = *reinterpret_cast<const float4*>(bv + cb0);
      const float4 bl1 = *reinterpret_cast<const float4*>(bv + cb1);
      f32x4 s0, s1;
      s0[0] = bl0.x; s0[1] = bl0.y; s0[2] = bl0.z; s0[3] = bl0.w;
      s1[0] = bl1.x; s1[1] = bl1.y; s1[2] = bl1.z; s1[3] = bl1.w;
#pragma unroll
      for (int mt = 0; mt < 4; ++mt) { acc[mt][0] = s0; acc[mt][1] = s1; }
    }
#pragma unroll
    for (int kc = 0; kc < 8; ++kc) {
      if (kc >= kcN) break;
      half8 wa0 = ldh8(&wa[wrow0 + kc * 32 + ko]);
      half8 wa1 = ldh8(&wa[wrow1 + kc * 32 + ko]);
      if (kc < 4) {
#pragma unroll
        for (int mt = 0; mt < 4; ++mt) {
          if (mt < mtiles) {
            half8 bx = ldh8(&x_lds[(mt * 16 + l15) * XSTR + kc * 32 + ko]);
            acc[mt][0] = MFMA16(wa0, bx, acc[mt][0]);
            acc[mt][1] = MFMA16(wa1, bx, acc[mt][1]);
          }
        }
      } else {
        // phi fragment: same in all lanes -> adds (phi @ Wb)[c] to every row
        half8 ph = ldh8(&phib[(kc - 4) * 32 + ko]);
#pragma unroll
        for (int mt = 0; mt < 4; ++mt) {
          if (mt < mtiles) {
            acc[mt][0] = MFMA16(wa0, ph, acc[mt][0]);
            acc[mt][1] = MFMA16(wa1, ph, acc[mt][1]);
          }
        }
      }
    }

    // ---- LN stats: in-lane 8-col partial + xor16/xor32 -> wave partial ----
#pragma unroll
    for (int mt = 0; mt < 4; ++mt) {
      if (mt < mtiles) {
        const f32x4 a0 = acc[mt][0], a1 = acc[mt][1];
        float s = ((a0[0] + a0[1]) + (a0[2] + a0[3])) + ((a1[0] + a1[1]) + (a1[2] + a1[3]));
        float q = a0[0] * a0[0];
        q = fmaf(a0[1], a0[1], q); q = fmaf(a0[2], a0[2], q); q = fmaf(a0[3], a0[3], q);
        q = fmaf(a1[0], a1[0], q); q = fmaf(a1[1], a1[1], q);
        q = fmaf(a1[2], a1[2], q); q = fmaf(a1[3], a1[3], q);
        s += __shfl_xor(s, 16); q += __shfl_xor(q, 16);
        s += __shfl_xor(s, 32); q += __shfl_xor(q, 32);
        if (l < 16) stats_s[mt * 16 + l15][w] = make_float2(s, q);
      }
    }
    __syncthreads();

    // ---- epilogue: per-lane mu/rstd from the 4 wave partials (b128 pair),
    //      normalize+relu, write x' (f16), masked packed row-max ----
    const float4 gg0 = *reinterpret_cast<const float4*>(gv + cb0);
    const float4 gg1 = *reinterpret_cast<const float4*>(gv + cb1);
    const float4 eb0 = *reinterpret_cast<const float4*>(bev + cb0);
    const float4 eb1 = *reinterpret_cast<const float4*>(bev + cb1);
    uint32_t pm[4] = {0u, 0u, 0u, 0u};  // packed f16x2 col maxes (relu => 0 is identity)
#pragma unroll
    for (int mt = 0; mt < 4; ++mt) {
      if (mt < mtiles) {
        const int row = mt * 16 + l15;
        float4 r01 = *reinterpret_cast<const float4*>(&stats_s[row][0]);
        float4 r23 = *reinterpret_cast<const float4*>(&stats_s[row][2]);
        float s = (r01.x + r01.z) + (r23.x + r23.z);
        float q = (r01.y + r01.w) + (r23.y + r23.w);
        float mu = s * (1.0f / 128.0f);
        float var = q * (1.0f / 128.0f) - mu * mu;
        float rs = rsqrtf(var + 1e-5f);
        const bool valid = row < len;
        float v0 = fmaxf((acc[mt][0][0] - mu) * rs * gg0.x + eb0.x, 0.0f);
        float v1 = fmaxf((acc[mt][0][1] - mu) * rs * gg0.y + eb0.y, 0.0f);
        float v2 = fmaxf((acc[mt][0][2] - mu) * rs * gg0.z + eb0.z, 0.0f);
        float v3 = fmaxf((acc[mt][0][3] - mu) * rs * gg0.w + eb0.w, 0.0f);
        float u0 = fmaxf((acc[mt][1][0] - mu) * rs * gg1.x + eb1.x, 0.0f);
        float u1 = fmaxf((acc[mt][1][1] - mu) * rs * gg1.y + eb1.y, 0.0f);
        float u2 = fmaxf((acc[mt][1][2] - mu) * rs * gg1.z + eb1.z, 0.0f);
        float u3 = fmaxf((acc[mt][1][3] - mu) * rs * gg1.w + eb1.w, 0.0f);
        if (layer < 2) {
          half4v h0; h0[0] = (f16)v0; h0[1] = (f16)v1; h0[2] = (f16)v2; h0[3] = (f16)v3;
          half4v h1; h1[0] = (f16)u0; h1[1] = (f16)u1; h1[2] = (f16)u2; h1[3] = (f16)u3;
          *reinterpret_cast<half4v*>(&x_lds[row * XSTR + cb0]) = h0;
          *reinterpret_cast<half4v*>(&x_lds[row * XSTR + cb1]) = h1;
        }
        pm[0] = pkmax(pm[0], pk2(valid ? v0 : 0.0f, valid ? v1 : 0.0f));
        pm[1] = pkmax(pm[1], pk2(valid ? v2 : 0.0f, valid ? v3 : 0.0f));
        pm[2] = pkmax(pm[2], pk2(valid ? u0 : 0.0f, valid ? u1 : 0.0f));
        pm[3] = pkmax(pm[3], pk2(valid ? u2 : 0.0f, valid ? u3 : 0.0f));
      }
    }
    // reduce over the 16 l15 lanes (rows) — packed f16 max, 4 levels
#pragma unroll
    for (int d = 1; d <= 8; d <<= 1) {
#pragma unroll
      for (int j = 0; j < 4; ++j)
        pm[j] = pkmax(pm[j], (uint32_t)__shfl_xor((int)pm[j], d));
    }

    if (layer < 2) {
      if (l15 == 0) {  // phi for next layer (4 consecutive f16 per uint2)
        *reinterpret_cast<uint2*>(&phib[cb0]) = make_uint2(pm[0], pm[1]);
        *reinterpret_cast<uint2*>(&phib[cb1]) = make_uint2(pm[2], pm[3]);
      }
      __syncthreads();  // x' + phib ready for next layer
    } else {
      if (l15 == 0) {  // output = concat(phi3, phi3)
        PkU q0, q1, q2, q3;
        q0.u = pm[0]; q1.u = pm[1]; q2.u = pm[2]; q3.u = pm[3];
        float4 o0 = make_float4((float)q0.h[0], (float)q0.h[1], (float)q1.h[0], (float)q1.h[1]);
        float4 o1 = make_float4((float)q2.h[0], (float)q2.h[1], (float)q3.h[0], (float)q3.h[1]);
        float* op = out + (size_t)p * 256;
        *reinterpret_cast<float4*>(op + cb0) = o0;
        *reinterpret_cast<float4*>(op + cb1) = o1;
        *reinterpret_cast<float4*>(op + 128 + cb0) = o0;
        *reinterpret_cast<float4*>(op + 128 + cb1) = o1;
      }
    }
  }
}

extern "C" void kernel_launch(void* const* d_in, const int* in_sizes, int n_in,
                              void* d_out, int out_size, void* d_ws, size_t ws_size,
                              hipStream_t stream) {
  const float* hs  = (const float*)d_in[0];
  const int* lens  = (const int*)d_in[1];
  const float* W1  = (const float*)d_in[2];
  const float* b1  = (const float*)d_in[3];
  const float* g1  = (const float*)d_in[4];
  const float* be1 = (const float*)d_in[5];
  const float* W2  = (const float*)d_in[6];
  const float* b2  = (const float*)d_in[7];
  const float* g2  = (const float*)d_in[8];
  const float* be2 = (const float*)d_in[9];
  const float* W3  = (const float*)d_in[10];
  const float* b3  = (const float*)d_in[11];
  const float* g3  = (const float*)d_in[12];
  const float* be3 = (const float*)d_in[13];
  float* out = (float*)d_out;
  f16* wt = (f16*)d_ws;  // needs (17408 + 2*33792)*2 = 169984 B of scratch

  const int prep_total = W1_ELEMS + 2 * W23_ELEMS;
  prep_weights<<<(prep_total + 255) / 256, 256, 0, stream>>>(W1, W2, W3, wt);
  fused_subgraph<<<PCNT, 256, 0, stream>>>(hs, lens, wt,
                                           b1, g1, be1, b2, g2, be2, b3, g3, be3,
                                           out);
}

// Round 10
// 117.641 us; speedup vs baseline: 1.1420x; 1.1420x over previous
//
#include <hip/hip_runtime.h>
#include <stdint.h>

// Problem constants (fixed by the reference): P=8192, L=64, H=128.
#define PCNT 8192
#define LROW 64
#define HDIM 128
#define XSTR 136                    // x_lds k-stride (f16), 16B aligned
#define W1STR 136                   // W1^T k-stride (K=128 + 8 pad)
#define W23STR 264                  // W2^T/W3^T k-stride (K=256 + 8 pad)
#define W1_ELEMS (128 * W1STR)      // 17408
#define W23_ELEMS (128 * W23STR)    // 33792

typedef _Float16 f16;
typedef __attribute__((ext_vector_type(8))) _Float16 half8;
typedef __attribute__((ext_vector_type(4))) _Float16 half4v;
typedef __attribute__((ext_vector_type(2))) _Float16 half2v;
typedef __attribute__((ext_vector_type(4))) float f32x4;

#define MFMA16(A, B, C) __builtin_amdgcn_mfma_f32_16x16x32_f16((A), (B), (C), 0, 0, 0)

__device__ __forceinline__ half8 ldh8(const f16* p) {
  return *reinterpret_cast<const half8*>(p);
}

union PkU { uint32_t u; half2v h; };

__device__ __forceinline__ uint32_t pk2(float lo, float hi) {
  PkU a;
  a.h[0] = (f16)lo;
  a.h[1] = (f16)hi;
  return a.u;
}

__device__ __forceinline__ uint32_t pkmax(uint32_t a, uint32_t b) {
  uint32_t d;
  asm("v_pk_max_f16 %0, %1, %2" : "=v"(d) : "v"(a), "v"(b));
  return d;
}

// ---------------------------------------------------------------------------
// Prep: ws = 3 transposed fp16 weight buffers (fused-K layout):
//   buf0 @0:                 W1^T  [c][k], k<128 real, stride 136
//   buf1 @W1_ELEMS:          W2^T  [c][k], k<256 real (Wa2|Wb2), stride 264
//   buf2 @W1_ELEMS+W23_ELEMS W3^T  same, stride 264
// ---------------------------------------------------------------------------
__global__ void prep_weights(const float* __restrict__ W1,
                             const float* __restrict__ W2,
                             const float* __restrict__ W3,
                             f16* __restrict__ wt) {
  int idx = blockIdx.x * 256 + threadIdx.x;
  if (idx >= W1_ELEMS + 2 * W23_ELEMS) return;
  float v = 0.0f;
  if (idx < W1_ELEMS) {
    int c = idx / W1STR, k = idx - c * W1STR;
    if (k < 128) v = W1[k * 128 + c];
  } else {
    int rem = idx - W1_ELEMS;
    const float* W = (rem < W23_ELEMS) ? W2 : W3;
    if (rem >= W23_ELEMS) rem -= W23_ELEMS;
    int c = rem / W23STR, k = rem - c * W23STR;
    if (k < 256) v = W[k * 128 + c];
  }
  wt[idx] = (f16)v;
}

// stage one polyline's rows [0,16*mtiles): fp32 -> fp16, b128 LDS writes
__device__ __forceinline__ void stage_x(f16* __restrict__ x_lds,
                                        const float* __restrict__ hp,
                                        int mtiles, int tid) {
  for (int it = 0; it < mtiles; ++it) {
    int e = (it * 256 + tid) * 8;
    int r = e >> 7, c = e & 127;
    float4 va = *reinterpret_cast<const float4*>(hp + e);
    float4 vb = *reinterpret_cast<const float4*>(hp + e + 4);
    half8 hv;
    hv[0] = (f16)va.x; hv[1] = (f16)va.y; hv[2] = (f16)va.z; hv[3] = (f16)va.w;
    hv[4] = (f16)vb.x; hv[5] = (f16)vb.y; hv[6] = (f16)vb.z; hv[7] = (f16)vb.w;
    *reinterpret_cast<half8*>(&x_lds[r * XSTR + c]) = hv;
  }
}

// ---------------------------------------------------------------------------
// Fused kernel, transposed-D (R3 lineage), TWO polylines per block processed
// CONCURRENTLY: each weight fragment load feeds both polylines' GEMMs
// (halves L2 weight traffic + per-block fixed costs; block count 4096).
// Fused-K: layers 1/2 take k>=128 B-fragments uniform from phib (rank-1
// concat term). Bias seeds acc. One stats barrier + one phib barrier per
// layer shared by both polylines. __launch_bounds__(256,4), ~100 VGPR.
// ---------------------------------------------------------------------------
__global__ __launch_bounds__(256, 4)
void fused_subgraph(const float* __restrict__ hs,
                    const int* __restrict__ lens,
                    const f16* __restrict__ wt,
                    const float* __restrict__ b1, const float* __restrict__ g1, const float* __restrict__ be1,
                    const float* __restrict__ b2, const float* __restrict__ g2, const float* __restrict__ be2,
                    const float* __restrict__ b3, const float* __restrict__ g3, const float* __restrict__ be3,
                    float* __restrict__ out) {
  __shared__ __align__(16) f16 xA[LROW * XSTR];      // 17408 B
  __shared__ __align__(16) f16 xB[LROW * XSTR];      // 17408 B
  __shared__ __align__(16) float2 stats_s[2][LROW][4];  // [poly][row][wave], 4 KB
  __shared__ __align__(16) f16 phiA[HDIM];
  __shared__ __align__(16) f16 phiB[HDIM];

  const int tid = threadIdx.x;
  const int w = tid >> 6;   // wave 0..3
  const int l = tid & 63;   // lane
  const int pA = blockIdx.x * 2;
  const int pB = pA + 1;

  int lenA = lens[pA];
  lenA = (lenA < 1) ? 1 : (lenA > LROW ? LROW : lenA);
  const int mtA = (lenA + 15) >> 4;
  int lenB = lens[pB];
  lenB = (lenB < 1) ? 1 : (lenB > LROW ? LROW : lenB);
  const int mtB = (lenB + 15) >> 4;

  const int l15 = l & 15;
  const int lg = l >> 4;                    // lane group 0..3
  const int ko = lg * 8;                    // k offset within a 32-k tile
  const int cb0 = w * 32 + lg * 4;          // lane's col base, nt=0
  const int cb1 = cb0 + 16;                 // nt=1

  // ---- stage both polylines ----
  stage_x(xA, hs + (size_t)pA * (LROW * HDIM), mtA, tid);
  stage_x(xB, hs + (size_t)pB * (LROW * HDIM), mtB, tid);
  __syncthreads();

#pragma unroll
  for (int layer = 0; layer < 3; ++layer) {
    const float* gv  = (layer == 0) ? g1  : (layer == 1) ? g2  : g3;
    const float* bev = (layer == 0) ? be1 : (layer == 1) ? be2 : be3;
    const float* bv  = (layer == 0) ? b1  : (layer == 1) ? b2  : b3;
    const f16* wa = (layer == 0) ? wt
                   : (layer == 1) ? (wt + W1_ELEMS)
                                  : (wt + W1_ELEMS + W23_ELEMS);
    const int wstr = (layer == 0) ? W1STR : W23STR;
    const int kcN  = (layer == 0) ? 4 : 8;
    const int wrow0 = (w * 32 + l15) * wstr;
    const int wrow1 = wrow0 + 16 * wstr;

    // ---- GEMM both polylines: acc = bias + (x~ @ W~)^T, K=128/256 ----
    f32x4 aA[4][2], aB[4][2];
    {
      const float4 bl0 = *reinterpret_cast<const float4*>(bv + cb0);
      const float4 bl1 = *reinterpret_cast<const float4*>(bv + cb1);
      f32x4 s0, s1;
      s0[0] = bl0.x; s0[1] = bl0.y; s0[2] = bl0.z; s0[3] = bl0.w;
      s1[0] = bl1.x; s1[1] = bl1.y; s1[2] = bl1.z; s1[3] = bl1.w;
#pragma unroll
      for (int mt = 0; mt < 4; ++mt) {
        aA[mt][0] = s0; aA[mt][1] = s1;
        aB[mt][0] = s0; aB[mt][1] = s1;
      }
    }
#pragma unroll
    for (int kc = 0; kc < 8; ++kc) {
      if (kc >= kcN) break;
      half8 wa0 = ldh8(&wa[wrow0 + kc * 32 + ko]);   // one load, two polylines
      half8 wa1 = ldh8(&wa[wrow1 + kc * 32 + ko]);
      if (kc < 4) {
#pragma unroll
        for (int mt = 0; mt < 4; ++mt) {
          if (mt < mtA) {
            half8 bx = ldh8(&xA[(mt * 16 + l15) * XSTR + kc * 32 + ko]);
            aA[mt][0] = MFMA16(wa0, bx, aA[mt][0]);
            aA[mt][1] = MFMA16(wa1, bx, aA[mt][1]);
          }
        }
#pragma unroll
        for (int mt = 0; mt < 4; ++mt) {
          if (mt < mtB) {
            half8 bx = ldh8(&xB[(mt * 16 + l15) * XSTR + kc * 32 + ko]);
            aB[mt][0] = MFMA16(wa0, bx, aB[mt][0]);
            aB[mt][1] = MFMA16(wa1, bx, aB[mt][1]);
          }
        }
      } else {
        half8 phfA = ldh8(&phiA[(kc - 4) * 32 + ko]);  // uniform -> row-const
        half8 phfB = ldh8(&phiB[(kc - 4) * 32 + ko]);
#pragma unroll
        for (int mt = 0; mt < 4; ++mt) {
          if (mt < mtA) {
            aA[mt][0] = MFMA16(wa0, phfA, aA[mt][0]);
            aA[mt][1] = MFMA16(wa1, phfA, aA[mt][1]);
          }
        }
#pragma unroll
        for (int mt = 0; mt < 4; ++mt) {
          if (mt < mtB) {
            aB[mt][0] = MFMA16(wa0, phfB, aB[mt][0]);
            aB[mt][1] = MFMA16(wa1, phfB, aB[mt][1]);
          }
        }
      }
    }

    // ---- LN stats both polylines ----
#pragma unroll
    for (int mt = 0; mt < 4; ++mt) {
      if (mt < mtA) {
        const f32x4 a0 = aA[mt][0], a1 = aA[mt][1];
        float s = ((a0[0] + a0[1]) + (a0[2] + a0[3])) + ((a1[0] + a1[1]) + (a1[2] + a1[3]));
        float q = a0[0] * a0[0];
        q = fmaf(a0[1], a0[1], q); q = fmaf(a0[2], a0[2], q); q = fmaf(a0[3], a0[3], q);
        q = fmaf(a1[0], a1[0], q); q = fmaf(a1[1], a1[1], q);
        q = fmaf(a1[2], a1[2], q); q = fmaf(a1[3], a1[3], q);
        s += __shfl_xor(s, 16); q += __shfl_xor(q, 16);
        s += __shfl_xor(s, 32); q += __shfl_xor(q, 32);
        if (l < 16) stats_s[0][mt * 16 + l15][w] = make_float2(s, q);
      }
    }
#pragma unroll
    for (int mt = 0; mt < 4; ++mt) {
      if (mt < mtB) {
        const f32x4 a0 = aB[mt][0], a1 = aB[mt][1];
        float s = ((a0[0] + a0[1]) + (a0[2] + a0[3])) + ((a1[0] + a1[1]) + (a1[2] + a1[3]));
        float q = a0[0] * a0[0];
        q = fmaf(a0[1], a0[1], q); q = fmaf(a0[2], a0[2], q); q = fmaf(a0[3], a0[3], q);
        q = fmaf(a1[0], a1[0], q); q = fmaf(a1[1], a1[1], q);
        q = fmaf(a1[2], a1[2], q); q = fmaf(a1[3], a1[3], q);
        s += __shfl_xor(s, 16); q += __shfl_xor(q, 16);
        s += __shfl_xor(s, 32); q += __shfl_xor(q, 32);
        if (l < 16) stats_s[1][mt * 16 + l15][w] = make_float2(s, q);
      }
    }
    __syncthreads();

    // ---- epilogues (shared g/beta loads) ----
    const float4 gg0 = *reinterpret_cast<const float4*>(gv + cb0);
    const float4 gg1 = *reinterpret_cast<const float4*>(gv + cb1);
    const float4 eb0 = *reinterpret_cast<const float4*>(bev + cb0);
    const float4 eb1 = *reinterpret_cast<const float4*>(bev + cb1);

#pragma unroll
    for (int poly = 0; poly < 2; ++poly) {
      const int mtP = poly ? mtB : mtA;
      const int lenP = poly ? lenB : lenA;
      f16* xP = poly ? xB : xA;
      f16* phiP = poly ? phiB : phiA;
      uint32_t pm[4] = {0u, 0u, 0u, 0u};
#pragma unroll
      for (int mt = 0; mt < 4; ++mt) {
        if (mt < mtP) {
          const f32x4 a0 = poly ? aB[mt][0] : aA[mt][0];
          const f32x4 a1 = poly ? aB[mt][1] : aA[mt][1];
          const int row = mt * 16 + l15;
          float4 r01 = *reinterpret_cast<const float4*>(&stats_s[poly][row][0]);
          float4 r23 = *reinterpret_cast<const float4*>(&stats_s[poly][row][2]);
          float s = (r01.x + r01.z) + (r23.x + r23.z);
          float q = (r01.y + r01.w) + (r23.y + r23.w);
          float mu = s * (1.0f / 128.0f);
          float var = q * (1.0f / 128.0f) - mu * mu;
          float rs = rsqrtf(var + 1e-5f);
          const bool valid = row < lenP;
          float v0 = fmaxf((a0[0] - mu) * rs * gg0.x + eb0.x, 0.0f);
          float v1 = fmaxf((a0[1] - mu) * rs * gg0.y + eb0.y, 0.0f);
          float v2 = fmaxf((a0[2] - mu) * rs * gg0.z + eb0.z, 0.0f);
          float v3 = fmaxf((a0[3] - mu) * rs * gg0.w + eb0.w, 0.0f);
          float u0 = fmaxf((a1[0] - mu) * rs * gg1.x + eb1.x, 0.0f);
          float u1 = fmaxf((a1[1] - mu) * rs * gg1.y + eb1.y, 0.0f);
          float u2 = fmaxf((a1[2] - mu) * rs * gg1.z + eb1.z, 0.0f);
          float u3 = fmaxf((a1[3] - mu) * rs * gg1.w + eb1.w, 0.0f);
          if (layer < 2) {
            half4v h0; h0[0] = (f16)v0; h0[1] = (f16)v1; h0[2] = (f16)v2; h0[3] = (f16)v3;
            half4v h1; h1[0] = (f16)u0; h1[1] = (f16)u1; h1[2] = (f16)u2; h1[3] = (f16)u3;
            *reinterpret_cast<half4v*>(&xP[row * XSTR + cb0]) = h0;
            *reinterpret_cast<half4v*>(&xP[row * XSTR + cb1]) = h1;
          }
          pm[0] = pkmax(pm[0], pk2(valid ? v0 : 0.0f, valid ? v1 : 0.0f));
          pm[1] = pkmax(pm[1], pk2(valid ? v2 : 0.0f, valid ? v3 : 0.0f));
          pm[2] = pkmax(pm[2], pk2(valid ? u0 : 0.0f, valid ? u1 : 0.0f));
          pm[3] = pkmax(pm[3], pk2(valid ? u2 : 0.0f, valid ? u3 : 0.0f));
        }
      }
#pragma unroll
      for (int d = 1; d <= 8; d <<= 1) {
#pragma unroll
        for (int j = 0; j < 4; ++j)
          pm[j] = pkmax(pm[j], (uint32_t)__shfl_xor((int)pm[j], d));
      }

      if (layer < 2) {
        if (l15 == 0) {
          *reinterpret_cast<uint2*>(&phiP[cb0]) = make_uint2(pm[0], pm[1]);
          *reinterpret_cast<uint2*>(&phiP[cb1]) = make_uint2(pm[2], pm[3]);
        }
      } else {
        if (l15 == 0) {  // output = concat(phi3, phi3)
          PkU q0, q1, q2, q3;
          q0.u = pm[0]; q1.u = pm[1]; q2.u = pm[2]; q3.u = pm[3];
          float4 o0 = make_float4((float)q0.h[0], (float)q0.h[1], (float)q1.h[0], (float)q1.h[1]);
          float4 o1 = make_float4((float)q2.h[0], (float)q2.h[1], (float)q3.h[0], (float)q3.h[1]);
          float* op = out + (size_t)(poly ? pB : pA) * 256;
          *reinterpret_cast<float4*>(op + cb0) = o0;
          *reinterpret_cast<float4*>(op + cb1) = o1;
          *reinterpret_cast<float4*>(op + 128 + cb0) = o0;
          *reinterpret_cast<float4*>(op + 128 + cb1) = o1;
        }
      }
    }
    if (layer < 2) __syncthreads();  // x' + phi ready for next layer
  }
}

extern "C" void kernel_launch(void* const* d_in, const int* in_sizes, int n_in,
                              void* d_out, int out_size, void* d_ws, size_t ws_size,
                              hipStream_t stream) {
  const float* hs  = (const float*)d_in[0];
  const int* lens  = (const int*)d_in[1];
  const float* W1  = (const float*)d_in[2];
  const float* b1  = (const float*)d_in[3];
  const float* g1  = (const float*)d_in[4];
  const float* be1 = (const float*)d_in[5];
  const float* W2  = (const float*)d_in[6];
  const float* b2  = (const float*)d_in[7];
  const float* g2  = (const float*)d_in[8];
  const float* be2 = (const float*)d_in[9];
  const float* W3  = (const float*)d_in[10];
  const float* b3  = (const float*)d_in[11];
  const float* g3  = (const float*)d_in[12];
  const float* be3 = (const float*)d_in[13];
  float* out = (float*)d_out;
  f16* wt = (f16*)d_ws;  // needs (17408 + 2*33792)*2 = 169984 B of scratch

  const int prep_total = W1_ELEMS + 2 * W23_ELEMS;
  prep_weights<<<(prep_total + 255) / 256, 256, 0, stream>>>(W1, W2, W3, wt);
  fused_subgraph<<<PCNT / 2, 256, 0, stream>>>(hs, lens, wt,
                                               b1, g1, be1, b2, g2, be2, b3, g3, be3,
                                               out);
}